// Round 5
// baseline (1102.866 us; speedup 1.0000x reference)
//
#include <hip/hip_runtime.h>

// Problem dims (fixed by the reference setup)
#define Bn 8
#define Sn 2048
#define Dn 512
#define Gn 4
#define Cn 2048
#define DGn 128
#define Nn 16384  // B*S

// d_out layout (flat fp32, reference return order)
#define OFF_Q    0u        // quantize_st  [8,2048,512]  = 8388608
#define OFF_IND  8388608u  // ind_out      [8,2048,4]    = 65536 (float-encoded ints)
#define OFF_LOSS 8454144u  // commit_loss  scalar
#define OFF_CS   8454145u  // new_cluster_size [4,2048]  = 8192
#define OFF_AVG  8462337u  // new_embed_avg [4,2048,128] = 1048576
#define OFF_EMB  9510913u  // new_embed     [4,2048,128] = 1048576 (first 8192 temporarily hold ||E||^2)

__global__ void vq_init(const float* __restrict__ cs_in,
                        const float* __restrict__ avg_in,
                        float* __restrict__ out) {
    int i = blockIdx.x * 256 + threadIdx.x;
    if (i < Gn * Cn * DGn) out[OFF_AVG + i] = 0.8f * avg_in[i];
    if (i < Gn * Cn)       out[OFF_CS + i]  = 0.8f * cs_in[i];
    if (i == 0)            out[OFF_LOSS] = 0.0f;
}

// one wave per code row: ||E[g,c]||^2 -> stash at OFF_EMB (overwritten by finalize)
__global__ void vq_enorm(const float* __restrict__ embed,
                         float* __restrict__ out) {
    int gid  = blockIdx.x * 256 + threadIdx.x;
    int wave = gid >> 6;            // 0..8191
    int lane = gid & 63;
    const float* row = embed + (size_t)wave * DGn;
    float a = row[lane], b = row[lane + 64];
    float v = fmaf(a, a, b * b);
    #pragma unroll
    for (int off = 32; off; off >>= 1) v += __shfl_xor(v, off, 64);
    if (lane == 0) out[OFF_EMB + wave] = v;
}

// Main fused kernel: block = (g, 128-row tile) x 512 threads (16tr x 32tc).
// Tile: 128m x 256c per c-iteration; per-thread 8m x 8c (64 acc VGPRs, proven
// 128-VGPR-clean in R4). LDS = As 64K + Es 16K = exactly 80 KB -> 2 blocks/CU
// = 16 waves/CU (4/SIMD), double R4's latency hiding; barrier pairs halve.
// All LDS accesses <=2-way (free). idxf/red buffers alias dead As/Es.
__launch_bounds__(512, 4)
__global__ void vq_main(const float* __restrict__ x,
                        const float* __restrict__ embed,
                        float* __restrict__ out) {
    __shared__ float As[DGn][128];   // A transposed [k][m], 64 KB. bank = m%32 -> 2-way (free)
    __shared__ float Es[16][256];    // E k-slice [k][c], 16 KB.  bank = c%32 -> 2-way (free)

    const int t  = threadIdx.x;
    const int g  = blockIdx.x >> 7;
    const int n0 = (blockIdx.x & 127) * 128;
    const int tr = t & 15;           // m-lane: 0..15
    const int tc = t >> 4;           // c-lane: 0..31

    const float* xg = x + (size_t)n0 * Dn + g * DGn;
    const float* eg = embed + (size_t)g * Cn * DGn;
    const float* enorm_g = out + OFF_EMB + g * Cn;

    // ---- stage A transposed: lane-per-row mapping -> scalar writes 2-way (free) ----
    {
        const int arow = t & 127, ah = t >> 7;   // ah: 0..3
        const float* xrow = xg + (size_t)arow * Dn;
        #pragma unroll
        for (int j = 0; j < 8; ++j) {
            int q4 = ah + 4 * j;
            float4 v = *(const float4*)(xrow + q4 * 4);
            int k = q4 * 4;
            As[k+0][arow] = v.x; As[k+1][arow] = v.y; As[k+2][arow] = v.z; As[k+3][arow] = v.w;
        }
    }

    float bestv[8];
    int   besti[8];
    #pragma unroll
    for (int i = 0; i < 8; ++i) { bestv[i] = -3.4e38f; besti[i] = 0; }

    const int m0 = 4 * tr;           // m-quads: m0 and 64+m0
    const int cb = 4 * tc;           // c-quads: cb and 128+cb (within 256-wide tile)
    const int ec = t & 255;          // Es staging: code lane 0..255
    const int kh = (t >> 8) * 8;     // Es staging: k-half 0 or 8

    for (int c0 = 0; c0 < Cn; c0 += 256) {
        float acc[8][8];
        #pragma unroll
        for (int i = 0; i < 8; ++i)
            #pragma unroll
            for (int j = 0; j < 8; ++j) acc[i][j] = 0.f;

        for (int k0 = 0; k0 < DGn; k0 += 16) {
            __syncthreads();   // previous consumers of Es done (also covers initial As staging)
            // stage E k-slice [16][256]: thread owns (code ec, k-half kh): 8 floats.
            {
                const float* erow = eg + (size_t)(c0 + ec) * DGn + k0 + kh;
                float4 e0 = *(const float4*)(erow);
                float4 e1 = *(const float4*)(erow + 4);
                Es[kh+0][ec] = e0.x; Es[kh+1][ec] = e0.y; Es[kh+2][ec] = e0.z; Es[kh+3][ec] = e0.w;
                Es[kh+4][ec] = e1.x; Es[kh+5][ec] = e1.y; Es[kh+6][ec] = e1.z; Es[kh+7][ec] = e1.w;
            }
            __syncthreads();
            #pragma unroll
            for (int kk = 0; kk < 16; ++kk) {
                float4 a0 = *(const float4*)&As[k0+kk][m0];
                float4 a1 = *(const float4*)&As[k0+kk][64 + m0];
                float4 b0 = *(const float4*)&Es[kk][cb];
                float4 b1 = *(const float4*)&Es[kk][128 + cb];
                float av[8] = {a0.x,a0.y,a0.z,a0.w,a1.x,a1.y,a1.z,a1.w};
                float bv[8] = {b0.x,b0.y,b0.z,b0.w,b1.x,b1.y,b1.z,b1.w};
                #pragma unroll
                for (int i = 0; i < 8; ++i) {
                    float a = av[i];
                    #pragma unroll
                    for (int j = 0; j < 8; ++j)
                        acc[i][j] = fmaf(a, bv[j], acc[i][j]);
                }
            }
        }
        // running argmax: score = 2*f.E - ||E||^2 (||f||^2 constant per row, dropped).
        // Fully unrolled (rule #20: any runtime index on acc -> scratch).
        #pragma unroll
        for (int h = 0; h < 2; ++h) {
            #pragma unroll
            for (int jj = 0; jj < 4; ++jj) {
                int c = c0 + 128*h + cb + jj;
                float en = enorm_g[c];
                #pragma unroll
                for (int i = 0; i < 8; ++i) {
                    float di = fmaf(2.0f, acc[i][4*h + jj], -en);
                    if (di > bestv[i]) { bestv[i] = di; besti[i] = c; }
                }
            }
        }
    }

    // ---- cross-thread argmax reduce (alias dead As for red, dead Es for idxf) ----
    float* redv = &As[0][0];                 // 128*32 floats (16 KB)
    int*   redi = ((int*)&As[0][0]) + 4096;  // 128*32 ints   (16 KB)
    int*   idxf = (int*)&Es[0][0];           // 128 ints
    __syncthreads();
    #pragma unroll
    for (int i = 0; i < 8; ++i) {
        int m = (i < 4) ? (m0 + i) : (64 + m0 + i - 4);
        redv[m*32 + tc] = bestv[i];
        redi[m*32 + tc] = besti[i];
    }
    __syncthreads();
    if (t < 128) {
        float bv = redv[t*32]; int bi = redi[t*32];
        #pragma unroll
        for (int u = 1; u < 32; ++u) {
            float v2 = redv[t*32 + u]; int i2 = redi[t*32 + u];
            if (v2 > bv || (v2 == bv && i2 < bi)) { bv = v2; bi = i2; }
        }
        idxf[t] = bi;
        out[OFF_IND + (size_t)(n0 + t) * Gn + g] = (float)bi;
        atomicAdd(&out[OFF_CS + g*Cn + bi], 0.2f);
    }
    __syncthreads();

    // ---- quantize_st + embed_sum scatter + commit loss ----
    float lloss = 0.f;
    for (int j = 0; j < 32; ++j) {
        int e = j * 512 + t;
        int row = e >> 7, d = e & 127;
        int ci = idxf[row];
        float xv = xg[(size_t)row * Dn + d];
        float q  = eg[(size_t)ci * DGn + d];
        out[OFF_Q + (size_t)(n0+row) * Dn + g*DGn + d] = xv + (q - xv);
        atomicAdd(&out[OFF_AVG + ((size_t)g*Cn + ci)*DGn + d], 0.2f * xv);
        float df = q - xv;
        lloss += df * df;
    }
    #pragma unroll
    for (int off = 32; off; off >>= 1) lloss += __shfl_xor(lloss, off, 64);
    if ((t & 63) == 0) atomicAdd(&out[OFF_LOSS], lloss);
}

// per-g: total, laplace smoothing, new_embed = avg/smoothed; scale loss
__global__ void vq_finalize(float* __restrict__ out) {
    const int g = blockIdx.x >> 5;
    const int slice = blockIdx.x & 31;
    const int t = threadIdx.x;
    __shared__ float red[256];
    const float* ncs = out + OFF_CS + g * Cn;
    float s = 0.f;
    for (int c = t; c < Cn; c += 256) s += ncs[c];
    red[t] = s;
    __syncthreads();
    for (int w = 128; w; w >>= 1) {
        if (t < w) red[t] += red[t + w];
        __syncthreads();
    }
    float total = red[0];
    float denom = total + Cn * 1e-5f;
    const float* avg = out + OFF_AVG + (size_t)g * Cn * DGn;
    float* embo = out + OFF_EMB + (size_t)g * Cn * DGn;
    for (int u = 0; u < 32; ++u) {
        int e = slice * 8192 + u * 256 + t;
        int c = e >> 7;
        float sm = (ncs[c] + 1e-5f) / denom * total;
        embo[e] = avg[e] / sm;
    }
    if (blockIdx.x == 0 && t == 0) out[OFF_LOSS] *= (1.0f / 8388608.0f);
}

extern "C" void kernel_launch(void* const* d_in, const int* in_sizes, int n_in,
                              void* d_out, int out_size, void* d_ws, size_t ws_size,
                              hipStream_t stream) {
    const float* x    = (const float*)d_in[0];
    const float* emb  = (const float*)d_in[1];
    const float* cs   = (const float*)d_in[2];
    const float* eavg = (const float*)d_in[3];
    float* out = (float*)d_out;

    hipLaunchKernelGGL(vq_init,     dim3(4096), dim3(256), 0, stream, cs, eavg, out);
    hipLaunchKernelGGL(vq_enorm,    dim3(2048), dim3(256), 0, stream, emb, out);
    hipLaunchKernelGGL(vq_main,     dim3(512),  dim3(512), 0, stream, x, emb, out);
    hipLaunchKernelGGL(vq_finalize, dim3(128),  dim3(256), 0, stream, out);
}

// Round 6
// 508.139 us; speedup vs baseline: 2.1704x; 2.1704x over previous
//
#include <hip/hip_runtime.h>

// Problem dims (fixed by the reference setup)
#define Bn 8
#define Sn 2048
#define Dn 512
#define Gn 4
#define Cn 2048
#define DGn 128
#define Nn 16384  // B*S

// d_out layout (flat fp32, reference return order)
#define OFF_Q    0u        // quantize_st  [8,2048,512]  = 8388608
#define OFF_IND  8388608u  // ind_out      [8,2048,4]    = 65536 (float-encoded ints)
#define OFF_LOSS 8454144u  // commit_loss  scalar
#define OFF_CS   8454145u  // new_cluster_size [4,2048]  = 8192
#define OFF_AVG  8462337u  // new_embed_avg [4,2048,128] = 1048576
#define OFF_EMB  9510913u  // new_embed     [4,2048,128] = 1048576 (first 8192 temporarily hold ||E||^2)

__global__ void vq_init(const float* __restrict__ cs_in,
                        const float* __restrict__ avg_in,
                        float* __restrict__ out) {
    int i = blockIdx.x * 256 + threadIdx.x;
    if (i < Gn * Cn * DGn) out[OFF_AVG + i] = 0.8f * avg_in[i];
    if (i < Gn * Cn)       out[OFF_CS + i]  = 0.8f * cs_in[i];
    if (i == 0)            out[OFF_LOSS] = 0.0f;
}

// one wave per code row: ||E[g,c]||^2 -> stash at OFF_EMB (overwritten by finalize)
__global__ void vq_enorm(const float* __restrict__ embed,
                         float* __restrict__ out) {
    int gid  = blockIdx.x * 256 + threadIdx.x;
    int wave = gid >> 6;            // 0..8191
    int lane = gid & 63;
    const float* row = embed + (size_t)wave * DGn;
    float a = row[lane], b = row[lane + 64];
    float v = fmaf(a, a, b * b);
    #pragma unroll
    for (int off = 32; off; off >>= 1) v += __shfl_xor(v, off, 64);
    if (lane == 0) out[OFF_EMB + wave] = v;
}

// Main fused kernel: block = (g, 128-row tile) x 512 threads (16tr x 32tc).
// Tile: 128m x 256c; per-thread 8m x 8c (64 acc VGPRs — fits 128 cleanly, R4).
// __launch_bounds__(512, 2): empirically the 2nd arg acts as min BLOCKS/CU
// (R5: (512,4) -> VGPR_Count=64 = 32-wave cap -> 666 MB spill). 2 blocks/CU
// -> VGPR cap 128, LDS 80 KB -> 2 blocks co-resident = 4 waves/SIMD.
__launch_bounds__(512, 2)
__global__ void vq_main(const float* __restrict__ x,
                        const float* __restrict__ embed,
                        float* __restrict__ out) {
    __shared__ float As[DGn][128];   // A transposed [k][m], 64 KB. bank = m%32 -> 2-way (free)
    __shared__ float Es[16][256];    // E k-slice [k][c], 16 KB.  bank = c%32 -> 2-way (free)

    const int t  = threadIdx.x;
    const int g  = blockIdx.x >> 7;
    const int n0 = (blockIdx.x & 127) * 128;
    const int tr = t & 15;           // m-lane: 0..15
    const int tc = t >> 4;           // c-lane: 0..31

    const float* xg = x + (size_t)n0 * Dn + g * DGn;
    const float* eg = embed + (size_t)g * Cn * DGn;
    const float* enorm_g = out + OFF_EMB + g * Cn;

    // ---- stage A transposed: lane-per-row mapping -> scalar writes 2-way (free) ----
    {
        const int arow = t & 127, ah = t >> 7;   // ah: 0..3
        const float* xrow = xg + (size_t)arow * Dn;
        #pragma unroll
        for (int j = 0; j < 8; ++j) {
            int q4 = ah + 4 * j;
            float4 v = *(const float4*)(xrow + q4 * 4);
            int k = q4 * 4;
            As[k+0][arow] = v.x; As[k+1][arow] = v.y; As[k+2][arow] = v.z; As[k+3][arow] = v.w;
        }
    }

    float bestv[8];
    int   besti[8];
    #pragma unroll
    for (int i = 0; i < 8; ++i) { bestv[i] = -3.4e38f; besti[i] = 0; }

    const int m0 = 4 * tr;           // m-quads: m0 and 64+m0
    const int cb = 4 * tc;           // c-quads: cb and 128+cb (within 256-wide tile)
    const int ec = t & 255;          // Es staging: code lane 0..255
    const int kh = (t >> 8) * 8;     // Es staging: k-half 0 or 8

    for (int c0 = 0; c0 < Cn; c0 += 256) {
        float acc[8][8];
        #pragma unroll
        for (int i = 0; i < 8; ++i)
            #pragma unroll
            for (int j = 0; j < 8; ++j) acc[i][j] = 0.f;

        for (int k0 = 0; k0 < DGn; k0 += 16) {
            __syncthreads();   // previous consumers of Es done (also covers initial As staging)
            // stage E k-slice [16][256]: thread owns (code ec, k-half kh): 8 floats.
            {
                const float* erow = eg + (size_t)(c0 + ec) * DGn + k0 + kh;
                float4 e0 = *(const float4*)(erow);
                float4 e1 = *(const float4*)(erow + 4);
                Es[kh+0][ec] = e0.x; Es[kh+1][ec] = e0.y; Es[kh+2][ec] = e0.z; Es[kh+3][ec] = e0.w;
                Es[kh+4][ec] = e1.x; Es[kh+5][ec] = e1.y; Es[kh+6][ec] = e1.z; Es[kh+7][ec] = e1.w;
            }
            __syncthreads();
            #pragma unroll
            for (int kk = 0; kk < 16; ++kk) {
                float4 a0 = *(const float4*)&As[k0+kk][m0];
                float4 a1 = *(const float4*)&As[k0+kk][64 + m0];
                float4 b0 = *(const float4*)&Es[kk][cb];
                float4 b1 = *(const float4*)&Es[kk][128 + cb];
                float av[8] = {a0.x,a0.y,a0.z,a0.w,a1.x,a1.y,a1.z,a1.w};
                float bv[8] = {b0.x,b0.y,b0.z,b0.w,b1.x,b1.y,b1.z,b1.w};
                #pragma unroll
                for (int i = 0; i < 8; ++i) {
                    float a = av[i];
                    #pragma unroll
                    for (int j = 0; j < 8; ++j)
                        acc[i][j] = fmaf(a, bv[j], acc[i][j]);
                }
            }
        }
        // running argmax: score = 2*f.E - ||E||^2 (||f||^2 constant per row, dropped).
        // Fully unrolled (rule #20: any runtime index on acc -> scratch).
        #pragma unroll
        for (int h = 0; h < 2; ++h) {
            #pragma unroll
            for (int jj = 0; jj < 4; ++jj) {
                int c = c0 + 128*h + cb + jj;
                float en = enorm_g[c];
                #pragma unroll
                for (int i = 0; i < 8; ++i) {
                    float di = fmaf(2.0f, acc[i][4*h + jj], -en);
                    if (di > bestv[i]) { bestv[i] = di; besti[i] = c; }
                }
            }
        }
    }

    // ---- cross-thread argmax reduce (alias dead As for red, dead Es for idxf) ----
    // stride 33 (not 32): stride-32 puts bank = tc for all 16 writers -> 16-way.
    float* redv = &As[0][0];                 // 128*33 floats
    int*   redi = ((int*)&As[0][0]) + 4352;  // 128*33 ints
    int*   idxf = (int*)&Es[0][0];           // 128 ints
    __syncthreads();
    #pragma unroll
    for (int i = 0; i < 8; ++i) {
        int m = (i < 4) ? (m0 + i) : (64 + m0 + i - 4);
        redv[m*33 + tc] = bestv[i];
        redi[m*33 + tc] = besti[i];
    }
    __syncthreads();
    if (t < 128) {
        float bv = redv[t*33]; int bi = redi[t*33];
        #pragma unroll
        for (int u = 1; u < 32; ++u) {
            float v2 = redv[t*33 + u]; int i2 = redi[t*33 + u];
            if (v2 > bv || (v2 == bv && i2 < bi)) { bv = v2; bi = i2; }
        }
        idxf[t] = bi;
        out[OFF_IND + (size_t)(n0 + t) * Gn + g] = (float)bi;
        atomicAdd(&out[OFF_CS + g*Cn + bi], 0.2f);
    }
    __syncthreads();

    // ---- quantize_st + embed_sum scatter + commit loss ----
    float lloss = 0.f;
    for (int j = 0; j < 32; ++j) {
        int e = j * 512 + t;
        int row = e >> 7, d = e & 127;
        int ci = idxf[row];
        float xv = xg[(size_t)row * Dn + d];
        float q  = eg[(size_t)ci * DGn + d];
        out[OFF_Q + (size_t)(n0+row) * Dn + g*DGn + d] = xv + (q - xv);
        atomicAdd(&out[OFF_AVG + ((size_t)g*Cn + ci)*DGn + d], 0.2f * xv);
        float df = q - xv;
        lloss += df * df;
    }
    #pragma unroll
    for (int off = 32; off; off >>= 1) lloss += __shfl_xor(lloss, off, 64);
    if ((t & 63) == 0) atomicAdd(&out[OFF_LOSS], lloss);
}

// per-g: total, laplace smoothing, new_embed = avg/smoothed; scale loss
__global__ void vq_finalize(float* __restrict__ out) {
    const int g = blockIdx.x >> 5;
    const int slice = blockIdx.x & 31;
    const int t = threadIdx.x;
    __shared__ float red[256];
    const float* ncs = out + OFF_CS + g * Cn;
    float s = 0.f;
    for (int c = t; c < Cn; c += 256) s += ncs[c];
    red[t] = s;
    __syncthreads();
    for (int w = 128; w; w >>= 1) {
        if (t < w) red[t] += red[t + w];
        __syncthreads();
    }
    float total = red[0];
    float denom = total + Cn * 1e-5f;
    const float* avg = out + OFF_AVG + (size_t)g * Cn * DGn;
    float* embo = out + OFF_EMB + (size_t)g * Cn * DGn;
    for (int u = 0; u < 32; ++u) {
        int e = slice * 8192 + u * 256 + t;
        int c = e >> 7;
        float sm = (ncs[c] + 1e-5f) / denom * total;
        embo[e] = avg[e] / sm;
    }
    if (blockIdx.x == 0 && t == 0) out[OFF_LOSS] *= (1.0f / 8388608.0f);
}

extern "C" void kernel_launch(void* const* d_in, const int* in_sizes, int n_in,
                              void* d_out, int out_size, void* d_ws, size_t ws_size,
                              hipStream_t stream) {
    const float* x    = (const float*)d_in[0];
    const float* emb  = (const float*)d_in[1];
    const float* cs   = (const float*)d_in[2];
    const float* eavg = (const float*)d_in[3];
    float* out = (float*)d_out;

    hipLaunchKernelGGL(vq_init,     dim3(4096), dim3(256), 0, stream, cs, eavg, out);
    hipLaunchKernelGGL(vq_enorm,    dim3(2048), dim3(256), 0, stream, emb, out);
    hipLaunchKernelGGL(vq_main,     dim3(512),  dim3(512), 0, stream, x, emb, out);
    hipLaunchKernelGGL(vq_finalize, dim3(128),  dim3(256), 0, stream, out);
}